// Round 8
// baseline (3625.459 us; speedup 1.0000x reference)
//
#include <hip/hip_runtime.h>
#include <math.h>

#define HH 4
#define CC 32
#define HC 128

__device__ __forceinline__ float relu4x(float v) { return fmaxf(v, 0.f); }

// =================== node projection: customer_x[101] -> user_x[32] ===================
__global__ __launch_bounds__(256) void k_proj101(
    const float* __restrict__ X, const float* __restrict__ W,
    const float* __restrict__ b, float* __restrict__ Y, int N) {
  __shared__ float xs[64][105];    // stride 105: (9r+k)%32 -> conflict-free scalar reads
  __shared__ float Ws[101 * 32];
  __shared__ float bs[32];
  for (int i = threadIdx.x; i < 101 * 32; i += 256) Ws[i] = W[i];
  if (threadIdx.x < 32) bs[threadIdx.x] = b[threadIdx.x];
  int row0 = blockIdx.x * 64;
  for (int idx = threadIdx.x; idx < 64 * 25; idx += 256) {
    int f = idx % 25, r = idx / 25;
    int row = row0 + r;
    float4 v = make_float4(0.f, 0.f, 0.f, 0.f);
    if (row < N) v = *(const float4*)(X + (size_t)row * 101 + f * 4);
    xs[r][f * 4 + 0] = v.x; xs[r][f * 4 + 1] = v.y;
    xs[r][f * 4 + 2] = v.z; xs[r][f * 4 + 3] = v.w;
  }
  if (threadIdx.x < 64) {
    int row = row0 + threadIdx.x;
    xs[threadIdx.x][100] = (row < N) ? X[(size_t)row * 101 + 100] : 0.f;
  }
  __syncthreads();
  int q = threadIdx.x & 3;
  int r = threadIdx.x >> 2;
  float acc[8];
#pragma unroll
  for (int j = 0; j < 8; ++j) acc[j] = bs[q * 8 + j];
  for (int k = 0; k < 101; ++k) {
    float xv = xs[r][k];
    float4 w0 = *(const float4*)&Ws[k * 32 + q * 8];
    float4 w1 = *(const float4*)&Ws[k * 32 + q * 8 + 4];
    acc[0] += xv * w0.x; acc[1] += xv * w0.y; acc[2] += xv * w0.z; acc[3] += xv * w0.w;
    acc[4] += xv * w1.x; acc[5] += xv * w1.y; acc[6] += xv * w1.z; acc[7] += xv * w1.w;
  }
  int row = row0 + r;
  if (row < N) {
    float* yr = Y + (size_t)row * 32 + q * 8;
    *(float4*)yr = make_float4(acc[0], acc[1], acc[2], acc[3]);
    *(float4*)(yr + 4) = make_float4(acc[4], acc[5], acc[6], acc[7]);
  }
}

__global__ __launch_bounds__(256) void k_item_proj(
    const float* __restrict__ X, const float* __restrict__ W,
    const float* __restrict__ b, float* __restrict__ Y, int N) {
  int t = blockIdx.x * 256 + threadIdx.x;
  if (t >= N * 32) return;
  int i = t >> 5, c = t & 31;
  Y[t] = X[i] * W[c] + b[c];
}

// ---- conflict-free X tile staging ----
// xs[r][4*(f ^ ((r>>3)&7)) .. +3] : float4 writes, 8 dwords/bank (min).
// read granule g of row r at 4*(g ^ ((r>>3)&7)).

// =================== K-chunked tiled GEMM (8x8 micro-tile, swizzled LDS) ===================
template <int K, int INRELU, int OUTRELU>
__global__ __launch_bounds__(256, 3) void k_tile(
    const float* __restrict__ X, const float* __restrict__ inb,
    const float* __restrict__ W, const float* __restrict__ b,
    float* __restrict__ Y, int N) {
  constexpr int KB = 32;
  constexpr int NCH = K / KB;
  __shared__ float xs[128][36];
  __shared__ float ws[KB][128];
  __shared__ float bsl[128];
  __shared__ float inbs[K];
  for (int i = threadIdx.x; i < 128; i += 256) bsl[i] = b[i];
  for (int i = threadIdx.x; i < K; i += 256) inbs[i] = inb ? inb[i] : 0.f;
  __syncthreads();
  int row0 = blockIdx.x * 128;
  int tx = threadIdx.x & 15, ty = threadIdx.x >> 4;
  int cswz = ty & 7;
  float acc[8][8];
#pragma unroll
  for (int j = 0; j < 4; ++j) {
    float b0 = bsl[tx * 4 + j], b1 = bsl[64 + tx * 4 + j];
#pragma unroll
    for (int i = 0; i < 8; ++i) { acc[i][j] = b0; acc[i][4 + j] = b1; }
  }
  for (int ch = 0; ch < NCH; ++ch) {
    int k0 = ch * KB;
    for (int idx = threadIdx.x; idx < 128 * 8; idx += 256) {
      int f = idx & 7, r = idx >> 3;
      int row = row0 + r;
      float4 v = make_float4(0.f, 0.f, 0.f, 0.f);
      if (row < N) {
        v = *(const float4*)(X + (size_t)row * K + k0 + f * 4);
        v.x += inbs[k0 + f * 4 + 0]; v.y += inbs[k0 + f * 4 + 1];
        v.z += inbs[k0 + f * 4 + 2]; v.w += inbs[k0 + f * 4 + 3];
        if (INRELU) { v.x = relu4x(v.x); v.y = relu4x(v.y); v.z = relu4x(v.z); v.w = relu4x(v.w); }
      }
      *(float4*)&xs[r][4 * (f ^ ((r >> 3) & 7))] = v;
    }
    for (int idx = threadIdx.x; idx < KB * 32; idx += 256) {
      int c4 = (idx & 31) * 4, kk = idx >> 5;
      *(float4*)&ws[kk][c4] = *(const float4*)(W + (size_t)(k0 + kk) * 128 + c4);
    }
    __syncthreads();
#pragma unroll
    for (int g = 0; g < 8; ++g) {
      float4 a4[8];
#pragma unroll
      for (int i = 0; i < 8; ++i)
        a4[i] = *(const float4*)&xs[ty * 8 + i][4 * (g ^ cswz)];
#pragma unroll
      for (int kk = 0; kk < 4; ++kk) {
        int k = g * 4 + kk;
        float4 b0 = *(const float4*)&ws[k][tx * 4];
        float4 b1 = *(const float4*)&ws[k][64 + tx * 4];
        float bv[8] = {b0.x, b0.y, b0.z, b0.w, b1.x, b1.y, b1.z, b1.w};
#pragma unroll
        for (int i = 0; i < 8; ++i) {
          float av = (kk == 0) ? a4[i].x : (kk == 1) ? a4[i].y : (kk == 2) ? a4[i].z : a4[i].w;
#pragma unroll
          for (int j = 0; j < 8; ++j) acc[i][j] += av * bv[j];
        }
      }
    }
    __syncthreads();
  }
#pragma unroll
  for (int i = 0; i < 8; ++i) {
    int row = row0 + ty * 8 + i;
    if (row < N) {
      float o[8];
#pragma unroll
      for (int j = 0; j < 8; ++j) o[j] = OUTRELU ? fmaxf(acc[i][j], 0.f) : acc[i][j];
      float* yr = Y + (size_t)row * 128;
      *(float4*)(yr + tx * 4) = make_float4(o[0], o[1], o[2], o[3]);
      *(float4*)(yr + 64 + tx * 4) = make_float4(o[4], o[5], o[6], o[7]);
    }
  }
}

// =================== dual K=32 GEMM (swizzled LDS) ===================
__global__ __launch_bounds__(256, 2) void k_dual32(
    const float* __restrict__ X,
    const float* __restrict__ W1, const float* __restrict__ b1,
    const float* __restrict__ W2, const float* __restrict__ b2,
    float* __restrict__ Y1, float* __restrict__ Y2, int N) {
  __shared__ float xs[128][36];
  __shared__ float ws1[32][128];
  __shared__ float ws2[32][128];
  __shared__ float bsa[128];
  __shared__ float bsb[128];
  for (int i = threadIdx.x; i < 128; i += 256) { bsa[i] = b1[i]; bsb[i] = b2[i]; }
  int row0 = blockIdx.x * 128;
  for (int idx = threadIdx.x; idx < 128 * 8; idx += 256) {
    int f = idx & 7, r = idx >> 3;
    int row = row0 + r;
    float4 v = make_float4(0.f, 0.f, 0.f, 0.f);
    if (row < N) v = *(const float4*)(X + (size_t)row * 32 + f * 4);
    *(float4*)&xs[r][4 * (f ^ ((r >> 3) & 7))] = v;
  }
  for (int idx = threadIdx.x; idx < 32 * 32; idx += 256) {
    int c4 = (idx & 31) * 4, kk = idx >> 5;
    *(float4*)&ws1[kk][c4] = *(const float4*)(W1 + (size_t)kk * 128 + c4);
    *(float4*)&ws2[kk][c4] = *(const float4*)(W2 + (size_t)kk * 128 + c4);
  }
  __syncthreads();
  int tx = threadIdx.x & 15, ty = threadIdx.x >> 4;
  int cswz = ty & 7;
  float acc1[8][8], acc2[8][8];
#pragma unroll
  for (int j = 0; j < 4; ++j) {
    float p0 = bsa[tx * 4 + j], p1 = bsa[64 + tx * 4 + j];
    float q0 = bsb[tx * 4 + j], q1 = bsb[64 + tx * 4 + j];
#pragma unroll
    for (int i = 0; i < 8; ++i) {
      acc1[i][j] = p0; acc1[i][4 + j] = p1;
      acc2[i][j] = q0; acc2[i][4 + j] = q1;
    }
  }
#pragma unroll
  for (int g = 0; g < 8; ++g) {
    float4 a4[8];
#pragma unroll
    for (int i = 0; i < 8; ++i)
      a4[i] = *(const float4*)&xs[ty * 8 + i][4 * (g ^ cswz)];
#pragma unroll
    for (int kk = 0; kk < 4; ++kk) {
      int k = g * 4 + kk;
      float4 p0 = *(const float4*)&ws1[k][tx * 4];
      float4 p1 = *(const float4*)&ws1[k][64 + tx * 4];
      float4 q0 = *(const float4*)&ws2[k][tx * 4];
      float4 q1 = *(const float4*)&ws2[k][64 + tx * 4];
      float pv[8] = {p0.x, p0.y, p0.z, p0.w, p1.x, p1.y, p1.z, p1.w};
      float qv[8] = {q0.x, q0.y, q0.z, q0.w, q1.x, q1.y, q1.z, q1.w};
#pragma unroll
      for (int i = 0; i < 8; ++i) {
        float av = (kk == 0) ? a4[i].x : (kk == 1) ? a4[i].y : (kk == 2) ? a4[i].z : a4[i].w;
#pragma unroll
        for (int j = 0; j < 8; ++j) { acc1[i][j] += av * pv[j]; acc2[i][j] += av * qv[j]; }
      }
    }
  }
#pragma unroll
  for (int i = 0; i < 8; ++i) {
    int row = row0 + ty * 8 + i;
    if (row < N) {
      float* y1 = Y1 + (size_t)row * 128;
      float* y2 = Y2 + (size_t)row * 128;
      *(float4*)(y1 + tx * 4) = make_float4(acc1[i][0], acc1[i][1], acc1[i][2], acc1[i][3]);
      *(float4*)(y1 + 64 + tx * 4) = make_float4(acc1[i][4], acc1[i][5], acc1[i][6], acc1[i][7]);
      *(float4*)(y2 + tx * 4) = make_float4(acc2[i][0], acc2[i][1], acc2[i][2], acc2[i][3]);
      *(float4*)(y2 + 64 + tx * 4) = make_float4(acc2[i][4], acc2[i][5], acc2[i][6], acc2[i][7]);
    }
  }
}

// =================== fully fused head (swizzled LDS, static reg indexing) ===================
__global__ __launch_bounds__(256, 3) void k_head_fused(
    const float* __restrict__ X, const float* __restrict__ inb,
    const float* __restrict__ W1, const float* __restrict__ b1,
    const float* __restrict__ W2, const float* __restrict__ b2,
    const float* __restrict__ Wc1, const float* __restrict__ bc1,
    const float* __restrict__ Wc2, const float* __restrict__ bc2,
    float* __restrict__ Z, float* __restrict__ S, int N) {
  __shared__ float xs[128][36];
  __shared__ float ws[32][128];
  __shared__ float ws2[32][64];
  __shared__ float bsl[128];
  __shared__ float inbs[128];
  __shared__ float bsc[64];
  __shared__ float wc2s[64];
  for (int i = threadIdx.x; i < 128; i += 256) { bsl[i] = b1[i]; inbs[i] = inb[i]; }
  if (threadIdx.x < 64) { bsc[threadIdx.x] = bc1[threadIdx.x]; wc2s[threadIdx.x] = Wc2[threadIdx.x]; }
  __syncthreads();
  int row0 = blockIdx.x * 128;
  int tx = threadIdx.x & 15, ty = threadIdx.x >> 4;
  int cswz = ty & 7;
  float acc[8][8], accc[8][4];
#pragma unroll
  for (int j = 0; j < 4; ++j) {
    float b0 = bsl[tx * 4 + j], b1v = bsl[64 + tx * 4 + j], bc = bsc[tx * 4 + j];
#pragma unroll
    for (int i = 0; i < 8; ++i) { acc[i][j] = b0; acc[i][4 + j] = b1v; accc[i][j] = bc; }
  }
  // -------- main loop: X pass feeds proj1 + cls1 --------
  for (int ch = 0; ch < 4; ++ch) {
    int k0 = ch * 32;
    for (int idx = threadIdx.x; idx < 128 * 8; idx += 256) {
      int f = idx & 7, r = idx >> 3;
      int row = row0 + r;
      float4 v = make_float4(0.f, 0.f, 0.f, 0.f);
      if (row < N) {
        v = *(const float4*)(X + (size_t)row * 128 + k0 + f * 4);
        v.x += inbs[k0 + f * 4 + 0]; v.y += inbs[k0 + f * 4 + 1];
        v.z += inbs[k0 + f * 4 + 2]; v.w += inbs[k0 + f * 4 + 3];
      }
      *(float4*)&xs[r][4 * (f ^ ((r >> 3) & 7))] = v;
    }
    for (int idx = threadIdx.x; idx < 32 * 32; idx += 256) {
      int c4 = (idx & 31) * 4, kk = idx >> 5;
      *(float4*)&ws[kk][c4] = *(const float4*)(W1 + (size_t)(k0 + kk) * 128 + c4);
    }
    for (int idx = threadIdx.x; idx < 32 * 16; idx += 256) {
      int c4 = (idx & 15) * 4, kk = idx >> 4;
      *(float4*)&ws2[kk][c4] = *(const float4*)(Wc1 + (size_t)(k0 + kk) * 64 + c4);
    }
    __syncthreads();
#pragma unroll
    for (int g = 0; g < 8; ++g) {
      float4 a4[8];
#pragma unroll
      for (int i = 0; i < 8; ++i)
        a4[i] = *(const float4*)&xs[ty * 8 + i][4 * (g ^ cswz)];
#pragma unroll
      for (int kk = 0; kk < 4; ++kk) {
        int k = g * 4 + kk;
        float4 b0 = *(const float4*)&ws[k][tx * 4];
        float4 b1v = *(const float4*)&ws[k][64 + tx * 4];
        float4 cv = *(const float4*)&ws2[k][tx * 4];
        float bv[8] = {b0.x, b0.y, b0.z, b0.w, b1v.x, b1v.y, b1v.z, b1v.w};
#pragma unroll
        for (int i = 0; i < 8; ++i) {
          float av = (kk == 0) ? a4[i].x : (kk == 1) ? a4[i].y : (kk == 2) ? a4[i].z : a4[i].w;
#pragma unroll
          for (int j = 0; j < 8; ++j) acc[i][j] += av * bv[j];
          accc[i][0] += av * cv.x; accc[i][1] += av * cv.y;
          accc[i][2] += av * cv.z; accc[i][3] += av * cv.w;
        }
      }
    }
    __syncthreads();
  }
  // -------- cls epilogue --------
  {
    float w2a = wc2s[tx * 4], w2b = wc2s[tx * 4 + 1], w2c = wc2s[tx * 4 + 2], w2d = wc2s[tx * 4 + 3];
    float bb2 = bc2[0];
#pragma unroll
    for (int i = 0; i < 8; ++i) {
      float p = fmaxf(accc[i][0], 0.f) * w2a + fmaxf(accc[i][1], 0.f) * w2b +
                fmaxf(accc[i][2], 0.f) * w2c + fmaxf(accc[i][3], 0.f) * w2d;
      p += __shfl_xor(p, 1, 16);
      p += __shfl_xor(p, 2, 16);
      p += __shfl_xor(p, 4, 16);
      p += __shfl_xor(p, 8, 16);
      int row = row0 + ty * 8 + i;
      if (row < N && tx == 0) S[row] = 1.f / (1.f + __expf(-(p + bb2)));
    }
  }
  // -------- phase C: out_z = relu(z1)@W2 + b2 --------
  // Column-half split: acc3[8][4] (32 regs) per half; ch fully unrolled so all
  // acc[][] indices are compile-time (rule #20: no scratch demotion).
#pragma unroll
  for (int half = 0; half < 2; ++half) {
    float acc3[8][4];
    float4 bb = *(const float4*)(b2 + half * 64 + tx * 4);
#pragma unroll
    for (int i = 0; i < 8; ++i) {
      acc3[i][0] = bb.x; acc3[i][1] = bb.y; acc3[i][2] = bb.z; acc3[i][3] = bb.w;
    }
#pragma unroll
    for (int ch = 0; ch < 4; ++ch) {
      // stage z1 chunk (cols 32ch..32ch+32) from acc into xs
      if ((tx >> 3) == (ch & 1)) {
        int gr = tx & 7;
        constexpr int jbs[4] = {0, 0, 4, 4};
        int jb = jbs[ch];  // ch is compile-time (unrolled)
#pragma unroll
        for (int i = 0; i < 8; ++i) {
          int r = ty * 8 + i;
          *(float4*)&xs[r][4 * (gr ^ cswz)] =
              make_float4(fmaxf(acc[i][jb + 0], 0.f), fmaxf(acc[i][jb + 1], 0.f),
                          fmaxf(acc[i][jb + 2], 0.f), fmaxf(acc[i][jb + 3], 0.f));
        }
      }
      // stage W2 half-chunk [32][64] into ws2
      for (int idx = threadIdx.x; idx < 32 * 16; idx += 256) {
        int c4 = (idx & 15) * 4, kk = idx >> 4;
        *(float4*)&ws2[kk][c4] =
            *(const float4*)(W2 + (size_t)(ch * 32 + kk) * 128 + half * 64 + c4);
      }
      __syncthreads();
#pragma unroll
      for (int g = 0; g < 8; ++g) {
        float4 a4[8];
#pragma unroll
        for (int i = 0; i < 8; ++i)
          a4[i] = *(const float4*)&xs[ty * 8 + i][4 * (g ^ cswz)];
#pragma unroll
        for (int kk = 0; kk < 4; ++kk) {
          int k = g * 4 + kk;
          float4 bv = *(const float4*)&ws2[k][tx * 4];
#pragma unroll
          for (int i = 0; i < 8; ++i) {
            float av = (kk == 0) ? a4[i].x : (kk == 1) ? a4[i].y : (kk == 2) ? a4[i].z : a4[i].w;
            acc3[i][0] += av * bv.x; acc3[i][1] += av * bv.y;
            acc3[i][2] += av * bv.z; acc3[i][3] += av * bv.w;
          }
        }
      }
      __syncthreads();
    }
#pragma unroll
    for (int i = 0; i < 8; ++i) {
      int row = row0 + ty * 8 + i;
      if (row < N)
        *(float4*)(Z + (size_t)row * 128 + half * 64 + tx * 4) =
            make_float4(acc3[i][0], acc3[i][1], acc3[i][2], acc3[i][3]);
    }
  }
}

// =================== CSR build (fused both directions) ===================

__global__ __launch_bounds__(256) void k_hist2(
    const int* __restrict__ src, const int* __restrict__ dst,
    int* __restrict__ histD, int* __restrict__ histS, int E) {
  int e = blockIdx.x * 256 + threadIdx.x;
  if (e >= E) return;
  atomicAdd(&histD[dst[e]], 1);
  atomicAdd(&histS[src[e]], 1);
}

#define SCAN_T 256
#define SCAN_V 4
#define SCAN_BLK 1024

__global__ __launch_bounds__(SCAN_T) void k_scan_local(
    const int* __restrict__ hist, int* __restrict__ starts,
    int* __restrict__ partials, int N) {
  __shared__ int sums[SCAN_T];
  int base = blockIdx.x * SCAN_BLK + threadIdx.x * SCAN_V;
  int v[SCAN_V];
  int s = 0;
#pragma unroll
  for (int i = 0; i < SCAN_V; ++i) { v[i] = (base + i < N) ? hist[base + i] : 0; s += v[i]; }
  sums[threadIdx.x] = s;
  __syncthreads();
  for (int off = 1; off < SCAN_T; off <<= 1) {
    int x = (threadIdx.x >= off) ? sums[threadIdx.x - off] : 0;
    __syncthreads();
    sums[threadIdx.x] += x;
    __syncthreads();
  }
  int run = (threadIdx.x > 0) ? sums[threadIdx.x - 1] : 0;
#pragma unroll
  for (int i = 0; i < SCAN_V; ++i) {
    if (base + i < N) starts[base + i] = run;
    run += v[i];
  }
  if (threadIdx.x == SCAN_T - 1) partials[blockIdx.x] = sums[SCAN_T - 1];
}

__global__ __launch_bounds__(SCAN_T) void k_scan_partials(int* partials, int nb) {
  __shared__ int s[SCAN_T];
  s[threadIdx.x] = (threadIdx.x < nb) ? partials[threadIdx.x] : 0;
  __syncthreads();
  for (int off = 1; off < SCAN_T; off <<= 1) {
    int x = (threadIdx.x >= off) ? s[threadIdx.x - off] : 0;
    __syncthreads();
    s[threadIdx.x] += x;
    __syncthreads();
  }
  if (threadIdx.x < nb) partials[threadIdx.x] = (threadIdx.x > 0) ? s[threadIdx.x - 1] : 0;
}

__global__ __launch_bounds__(256) void k_scan_add(
    int* __restrict__ starts, const int* __restrict__ partials,
    int* __restrict__ cursor, int N) {
  int i = blockIdx.x * 256 + threadIdx.x;
  if (i >= N) return;
  int v = starts[i] + partials[i / SCAN_BLK];
  starts[i] = v;
  cursor[i] = v;
}

__global__ __launch_bounds__(256) void k_scatter2(
    const int* __restrict__ src, const int* __restrict__ dst,
    int* __restrict__ cur1, int* __restrict__ cur2,
    int2* __restrict__ ebuf1, int2* __restrict__ ebuf2, int E) {
  int e = blockIdx.x * 256 + threadIdx.x;
  if (e >= E) return;
  int s = src[e], d = dst[e];
  int p1 = atomicAdd(&cur1[d], 1);
  ebuf1[p1] = make_int2(s, e);
  int p2 = atomicAdd(&cur2[s], 1);
  ebuf2[p2] = make_int2(d, e);
}

// =================== fused GATv2 edge phase (gather-only, online softmax) ===================
template <int USE_EF>
__global__ __launch_bounds__(256) void k_gat(
    const float* __restrict__ xl, const float* __restrict__ xr,
    const int2* __restrict__ ebuf, const int* __restrict__ starts,
    const int* __restrict__ counts, const float* __restrict__ att,
    const float* __restrict__ eattr, const float* __restrict__ We,
    float* __restrict__ agg, int N) {
  int wid = (blockIdx.x * 256 + threadIdx.x) >> 6;
  if (wid >= N) return;
  int lane = threadIdx.x & 63;
  int g = lane >> 4;
  int t = lane & 15;
  int c = g * 32 + t * 2;
  float att0 = att[c], att1 = att[c + 1];
  float2 we0, we1, we2;
  if (USE_EF) {
    we0 = *(const float2*)(We + 0 * HC + c);
    we1 = *(const float2*)(We + 1 * HC + c);
    we2 = *(const float2*)(We + 2 * HC + c);
  }
  float2 xrv = *(const float2*)(xr + (size_t)wid * HC + c);
  int st = starts[wid], cnt = counts[wid];
  float m = -3.402823466e38f, dsum = 0.f, a0 = 0.f, a1 = 0.f;
  for (int i = 0; i < cnt; ++i) {
    int2 se = ebuf[st + i];
    float2 xlv = *(const float2*)(xl + (size_t)se.x * HC + c);
    float x0 = xlv.x + xrv.x, x1 = xlv.y + xrv.y;
    if (USE_EF) {
      const float* ea = eattr + (size_t)se.y * 3;
      float e0 = ea[0], e1 = ea[1], e2 = ea[2];
      x0 += e0 * we0.x + e1 * we1.x + e2 * we2.x;
      x1 += e0 * we0.y + e1 * we1.y + e2 * we2.y;
    }
    x0 = (x0 > 0.f) ? x0 : 0.2f * x0;
    x1 = (x1 > 0.f) ? x1 : 0.2f * x1;
    float p = x0 * att0 + x1 * att1;
    p += __shfl_xor(p, 1, 16);
    p += __shfl_xor(p, 2, 16);
    p += __shfl_xor(p, 4, 16);
    p += __shfl_xor(p, 8, 16);
    float newm = fmaxf(m, p);
    float scale = __expf(m - newm);
    float w = __expf(p - newm);
    dsum = dsum * scale + w;
    a0 = a0 * scale + w * xlv.x;
    a1 = a1 * scale + w * xlv.y;
    m = newm;
  }
  float inv = (dsum > 0.f) ? 1.f / dsum : 0.f;
  *(float2*)(agg + (size_t)wid * HC + c) = make_float2(a0 * inv, a1 * inv);
}

static inline int imin(int a, int b) { return a < b ? a : b; }

extern "C" void kernel_launch(void* const* d_in, const int* in_sizes, int n_in,
                              void* d_out, int out_size, void* d_ws, size_t ws_size,
                              hipStream_t stream) {
  const float* customer_x = (const float*)d_in[0];
  const float* fund_x     = (const float*)d_in[1];
  const int*   edge_src   = (const int*)d_in[2];
  const int*   edge_dst   = (const int*)d_in[3];
  const float* edge_attr  = (const float*)d_in[4];
  const float* user_W = (const float*)d_in[5];
  const float* user_b = (const float*)d_in[6];
  const float* item_W = (const float*)d_in[7];
  const float* item_b = (const float*)d_in[8];
  const float* c1_Wl = (const float*)d_in[9];
  const float* c1_bl = (const float*)d_in[10];
  const float* c1_Wr = (const float*)d_in[11];
  const float* c1_br = (const float*)d_in[12];
  const float* c1_att = (const float*)d_in[13];
  const float* c1_We  = (const float*)d_in[14];
  const float* c1_bias = (const float*)d_in[15];
  const float* c2_Wl = (const float*)d_in[16];
  const float* c2_bl = (const float*)d_in[17];
  const float* c2_Wr = (const float*)d_in[18];
  const float* c2_br = (const float*)d_in[19];
  const float* c2_att = (const float*)d_in[20];
  const float* c2_bias = (const float*)d_in[21];
  const float* proj_W1 = (const float*)d_in[22];
  const float* proj_b1 = (const float*)d_in[23];
  const float* proj_W2 = (const float*)d_in[24];
  const float* proj_b2 = (const float*)d_in[25];
  const float* cls_W1 = (const float*)d_in[26];
  const float* cls_b1 = (const float*)d_in[27];
  const float* cls_W2 = (const float*)d_in[28];
  const float* cls_b2 = (const float*)d_in[29];

  const int Ncust = in_sizes[0] / 101;
  const int Nitem = in_sizes[1];
  const int E     = in_sizes[2];

  // -------- workspace layout (~141 MiB) --------
  float* w = (float*)d_ws;
  float* user_x  = w; w += (size_t)Ncust * 32;
  float* item_x0 = w; w += (size_t)Nitem * 32;
  float* bufC    = w; w += (size_t)Ncust * HC;   // xl1 -> (conv2 xl2 in first Nitem rows)
  float* bufD    = w; w += (size_t)Nitem * HC;   // xr1 -> agg1 (in-place)
  float* bufE    = w; w += (size_t)Ncust * HC;   // xr2 -> agg2 (in-place)
  int* hist1   = (int*)w; w += Nitem;            // hist1+hist2 adjacent: single memset
  int* hist2   = (int*)w; w += Ncust;
  int* starts1 = (int*)w; w += Nitem;
  int* cursor1 = (int*)w; w += Nitem;
  int* starts2 = (int*)w; w += Ncust;
  int* cursor2 = (int*)w; w += Ncust;
  int* partials = (int*)w; w += 512;
  int2* ebuf1 = (int2*)w; w += (size_t)E * 2;
  int2* ebuf2 = (int2*)w; w += (size_t)E * 2;
  if ((size_t)((char*)w - (char*)d_ws) > ws_size) return;

  float* out_scores = (float*)d_out;
  float* out_z      = out_scores + Ncust;

  const int egrid = (E + 255) / 256;
  const int nb1 = (Nitem + SCAN_BLK - 1) / SCAN_BLK;
  const int nb2 = (Ncust + SCAN_BLK - 1) / SCAN_BLK;
  const int nt1 = (Ncust + 127) / 128;
  const int nt2 = (Nitem + 127) / 128;

  // -------- CSR build (fused passes) --------
  hipMemsetAsync(hist1, 0, (size_t)(Nitem + Ncust) * 4, stream);
  k_hist2<<<egrid, 256, 0, stream>>>(edge_src, edge_dst, hist1, hist2, E);
  k_scan_local<<<nb1, SCAN_T, 0, stream>>>(hist1, starts1, partials, Nitem);
  k_scan_partials<<<1, SCAN_T, 0, stream>>>(partials, nb1);
  k_scan_add<<<(Nitem + 255) / 256, 256, 0, stream>>>(starts1, partials, cursor1, Nitem);
  k_scan_local<<<nb2, SCAN_T, 0, stream>>>(hist2, starts2, partials, Ncust);
  k_scan_partials<<<1, SCAN_T, 0, stream>>>(partials, nb2);
  k_scan_add<<<(Ncust + 255) / 256, 256, 0, stream>>>(starts2, partials, cursor2, Ncust);
  k_scatter2<<<egrid, 256, 0, stream>>>(edge_src, edge_dst, cursor1, cursor2, ebuf1, ebuf2, E);

  // -------- node projections --------
  k_proj101<<<(Ncust + 63) / 64, 256, 0, stream>>>(customer_x, user_W, user_b, user_x, Ncust);
  k_item_proj<<<(Nitem * 32 + 255) / 256, 256, 0, stream>>>(fund_x, item_W, item_b, item_x0, Nitem);

  // -------- conv linear parts from user_x (xl1 + xr2 in one pass) --------
  k_dual32<<<nt1, 256, 0, stream>>>(user_x, c1_Wl, c1_bl, c2_Wr, c2_br, bufC, bufE, Ncust);
  k_tile<32, 0, 0><<<nt2, 256, 0, stream>>>(item_x0, nullptr, c1_Wr, c1_br, bufD, Nitem);

  // -------- conv1 edge phase (customer -> fund), agg1 in-place into bufD --------
  k_gat<1><<<(Nitem + 3) / 4, 256, 0, stream>>>(bufC, bufD, ebuf1, starts1, hist1,
                                                c1_att, edge_attr, c1_We, bufD, Nitem);

  // -------- conv2: xl2 then edge phase (fund -> customer) in-place bufE --------
  k_tile<128, 1, 0><<<nt2, 256, 0, stream>>>(bufD, c1_bias, c2_Wl, c2_bl, bufC, Nitem);
  k_gat<0><<<(Ncust + 3) / 4, 256, 0, stream>>>(bufC, bufE, ebuf2, starts2, hist2,
                                                c2_att, nullptr, nullptr, bufE, Ncust);

  // -------- fused head: proj1 + cls + proj2 --------
  k_head_fused<<<nt1, 256, 0, stream>>>(bufE, c2_bias, proj_W1, proj_b1, proj_W2, proj_b2,
                                        cls_W1, cls_b1, cls_W2, cls_b2,
                                        out_z, out_scores, Ncust);
}

// Round 9
// 1787.986 us; speedup vs baseline: 2.0277x; 2.0277x over previous
//
#include <hip/hip_runtime.h>
#include <math.h>

#define HH 4
#define CC 32
#define HC 128

__device__ __forceinline__ float relu4x(float v) { return fmaxf(v, 0.f); }

// ---- xsT swizzle: element (k, r) stored at xsT[k][r ^ ((k>>2 & 3)<<3)].
// Staging writes: 2-way bank alias (free). Reads: broadcast float4, conflict-free.

// =================== node projection: customer_x[101] -> user_x[32] ===================
__global__ __launch_bounds__(256) void k_proj101(
    const float* __restrict__ X, const float* __restrict__ W,
    const float* __restrict__ b, float* __restrict__ Y, int N) {
  __shared__ float xs[64][105];
  __shared__ float Ws[101 * 32];
  __shared__ float bs[32];
  for (int i = threadIdx.x; i < 101 * 32; i += 256) Ws[i] = W[i];
  if (threadIdx.x < 32) bs[threadIdx.x] = b[threadIdx.x];
  int row0 = blockIdx.x * 64;
  for (int idx = threadIdx.x; idx < 64 * 25; idx += 256) {
    int f = idx % 25, r = idx / 25;
    int row = row0 + r;
    float4 v = make_float4(0.f, 0.f, 0.f, 0.f);
    if (row < N) v = *(const float4*)(X + (size_t)row * 101 + f * 4);
    xs[r][f * 4 + 0] = v.x; xs[r][f * 4 + 1] = v.y;
    xs[r][f * 4 + 2] = v.z; xs[r][f * 4 + 3] = v.w;
  }
  if (threadIdx.x < 64) {
    int row = row0 + threadIdx.x;
    xs[threadIdx.x][100] = (row < N) ? X[(size_t)row * 101 + 100] : 0.f;
  }
  __syncthreads();
  int q = threadIdx.x & 3;
  int r = threadIdx.x >> 2;
  float acc[8];
#pragma unroll
  for (int j = 0; j < 8; ++j) acc[j] = bs[q * 8 + j];
  for (int k = 0; k < 101; ++k) {
    float xv = xs[r][k];
    float4 w0 = *(const float4*)&Ws[k * 32 + q * 8];
    float4 w1 = *(const float4*)&Ws[k * 32 + q * 8 + 4];
    acc[0] += xv * w0.x; acc[1] += xv * w0.y; acc[2] += xv * w0.z; acc[3] += xv * w0.w;
    acc[4] += xv * w1.x; acc[5] += xv * w1.y; acc[6] += xv * w1.z; acc[7] += xv * w1.w;
  }
  int row = row0 + r;
  if (row < N) {
    float* yr = Y + (size_t)row * 32 + q * 8;
    *(float4*)yr = make_float4(acc[0], acc[1], acc[2], acc[3]);
    *(float4*)(yr + 4) = make_float4(acc[4], acc[5], acc[6], acc[7]);
  }
}

__global__ __launch_bounds__(256) void k_item_proj(
    const float* __restrict__ X, const float* __restrict__ W,
    const float* __restrict__ b, float* __restrict__ Y, int N) {
  int t = blockIdx.x * 256 + threadIdx.x;
  if (t >= N * 32) return;
  int i = t >> 5, c = t & 31;
  Y[t] = X[i] * W[c] + b[c];
}

// =================== K-chunked tiled GEMM (8x8 micro-tile, swizzled xsT, split cols) ===================
template <int K, int INRELU, int OUTRELU>
__global__ __launch_bounds__(256, 4) void k_tile(
    const float* __restrict__ X, const float* __restrict__ inb,
    const float* __restrict__ W, const float* __restrict__ b,
    float* __restrict__ Y, int N) {
  constexpr int KB = 32;
  constexpr int NCH = K / KB;
  __shared__ float xsT[KB][132];
  __shared__ float ws[KB][128];
  __shared__ float bsl[128];
  __shared__ float inbs[K];
  for (int i = threadIdx.x; i < 128; i += 256) bsl[i] = b[i];
  for (int i = threadIdx.x; i < K; i += 256) inbs[i] = inb ? inb[i] : 0.f;
  __syncthreads();
  int row0 = blockIdx.x * 128;
  int tx = threadIdx.x & 15, ty = threadIdx.x >> 4;
  int ty8 = ty * 8;
  float acc[8][8];
#pragma unroll
  for (int j = 0; j < 4; ++j) {
    float b0 = bsl[tx * 4 + j], b1 = bsl[64 + tx * 4 + j];
#pragma unroll
    for (int i = 0; i < 8; ++i) { acc[i][j] = b0; acc[i][4 + j] = b1; }
  }
  for (int ch = 0; ch < NCH; ++ch) {
    int k0 = ch * KB;
    for (int idx = threadIdx.x; idx < 128 * 8; idx += 256) {
      int f = idx & 7, r = idx >> 3;
      int row = row0 + r;
      float4 v = make_float4(0.f, 0.f, 0.f, 0.f);
      if (row < N) {
        v = *(const float4*)(X + (size_t)row * K + k0 + f * 4);
        v.x += inbs[k0 + f * 4 + 0]; v.y += inbs[k0 + f * 4 + 1];
        v.z += inbs[k0 + f * 4 + 2]; v.w += inbs[k0 + f * 4 + 3];
        if (INRELU) { v.x = relu4x(v.x); v.y = relu4x(v.y); v.z = relu4x(v.z); v.w = relu4x(v.w); }
      }
      int rx = r ^ ((f & 3) << 3);
      xsT[f * 4 + 0][rx] = v.x; xsT[f * 4 + 1][rx] = v.y;
      xsT[f * 4 + 2][rx] = v.z; xsT[f * 4 + 3][rx] = v.w;
    }
    for (int idx = threadIdx.x; idx < KB * 32; idx += 256) {
      int c4 = (idx & 31) * 4, kk = idx >> 5;
      *(float4*)&ws[kk][c4] = *(const float4*)(W + (size_t)(k0 + kk) * 128 + c4);
    }
    __syncthreads();
#pragma unroll
    for (int k = 0; k < KB; ++k) {
      int g8 = ((k >> 2) & 3) << 3;
      float4 a0 = *(const float4*)&xsT[k][(ty8 ^ g8)];
      float4 a1 = *(const float4*)&xsT[k][(ty8 ^ g8) + 4];
      float4 b0 = *(const float4*)&ws[k][tx * 4];
      float4 b1 = *(const float4*)&ws[k][64 + tx * 4];
      float av[8] = {a0.x, a0.y, a0.z, a0.w, a1.x, a1.y, a1.z, a1.w};
      float bv[8] = {b0.x, b0.y, b0.z, b0.w, b1.x, b1.y, b1.z, b1.w};
#pragma unroll
      for (int i = 0; i < 8; ++i)
#pragma unroll
        for (int j = 0; j < 8; ++j) acc[i][j] += av[i] * bv[j];
    }
    __syncthreads();
  }
#pragma unroll
  for (int i = 0; i < 8; ++i) {
    int row = row0 + ty8 + i;
    if (row < N) {
      float o[8];
#pragma unroll
      for (int j = 0; j < 8; ++j) o[j] = OUTRELU ? fmaxf(acc[i][j], 0.f) : acc[i][j];
      float* yr = Y + (size_t)row * 128;
      *(float4*)(yr + tx * 4) = make_float4(o[0], o[1], o[2], o[3]);
      *(float4*)(yr + 64 + tx * 4) = make_float4(o[4], o[5], o[6], o[7]);
    }
  }
}

// =================== dual K=32 GEMM (swizzled xsT, split cols) ===================
__global__ __launch_bounds__(256, 2) void k_dual32(
    const float* __restrict__ X,
    const float* __restrict__ W1, const float* __restrict__ b1,
    const float* __restrict__ W2, const float* __restrict__ b2,
    float* __restrict__ Y1, float* __restrict__ Y2, int N) {
  __shared__ float xsT[32][132];
  __shared__ float ws1[32][128];
  __shared__ float ws2[32][128];
  __shared__ float bsa[128];
  __shared__ float bsb[128];
  for (int i = threadIdx.x; i < 128; i += 256) { bsa[i] = b1[i]; bsb[i] = b2[i]; }
  int row0 = blockIdx.x * 128;
  for (int idx = threadIdx.x; idx < 128 * 8; idx += 256) {
    int f = idx & 7, r = idx >> 3;
    int row = row0 + r;
    float4 v = make_float4(0.f, 0.f, 0.f, 0.f);
    if (row < N) v = *(const float4*)(X + (size_t)row * 32 + f * 4);
    int rx = r ^ ((f & 3) << 3);
    xsT[f * 4 + 0][rx] = v.x; xsT[f * 4 + 1][rx] = v.y;
    xsT[f * 4 + 2][rx] = v.z; xsT[f * 4 + 3][rx] = v.w;
  }
  for (int idx = threadIdx.x; idx < 32 * 32; idx += 256) {
    int c4 = (idx & 31) * 4, kk = idx >> 5;
    *(float4*)&ws1[kk][c4] = *(const float4*)(W1 + (size_t)kk * 128 + c4);
    *(float4*)&ws2[kk][c4] = *(const float4*)(W2 + (size_t)kk * 128 + c4);
  }
  __syncthreads();
  int tx = threadIdx.x & 15, ty = threadIdx.x >> 4;
  int ty8 = ty * 8;
  float acc1[8][8], acc2[8][8];
#pragma unroll
  for (int j = 0; j < 4; ++j) {
    float p0 = bsa[tx * 4 + j], p1 = bsa[64 + tx * 4 + j];
    float q0 = bsb[tx * 4 + j], q1 = bsb[64 + tx * 4 + j];
#pragma unroll
    for (int i = 0; i < 8; ++i) {
      acc1[i][j] = p0; acc1[i][4 + j] = p1;
      acc2[i][j] = q0; acc2[i][4 + j] = q1;
    }
  }
#pragma unroll
  for (int k = 0; k < 32; ++k) {
    int g8 = ((k >> 2) & 3) << 3;
    float4 a0 = *(const float4*)&xsT[k][(ty8 ^ g8)];
    float4 a1 = *(const float4*)&xsT[k][(ty8 ^ g8) + 4];
    float4 p0 = *(const float4*)&ws1[k][tx * 4];
    float4 p1 = *(const float4*)&ws1[k][64 + tx * 4];
    float4 q0 = *(const float4*)&ws2[k][tx * 4];
    float4 q1 = *(const float4*)&ws2[k][64 + tx * 4];
    float av[8] = {a0.x, a0.y, a0.z, a0.w, a1.x, a1.y, a1.z, a1.w};
    float pv[8] = {p0.x, p0.y, p0.z, p0.w, p1.x, p1.y, p1.z, p1.w};
    float qv[8] = {q0.x, q0.y, q0.z, q0.w, q1.x, q1.y, q1.z, q1.w};
#pragma unroll
    for (int i = 0; i < 8; ++i)
#pragma unroll
      for (int j = 0; j < 8; ++j) { acc1[i][j] += av[i] * pv[j]; acc2[i][j] += av[i] * qv[j]; }
  }
#pragma unroll
  for (int i = 0; i < 8; ++i) {
    int row = row0 + ty8 + i;
    if (row < N) {
      float* y1 = Y1 + (size_t)row * 128;
      float* y2 = Y2 + (size_t)row * 128;
      *(float4*)(y1 + tx * 4) = make_float4(acc1[i][0], acc1[i][1], acc1[i][2], acc1[i][3]);
      *(float4*)(y1 + 64 + tx * 4) = make_float4(acc1[i][4], acc1[i][5], acc1[i][6], acc1[i][7]);
      *(float4*)(y2 + tx * 4) = make_float4(acc2[i][0], acc2[i][1], acc2[i][2], acc2[i][3]);
      *(float4*)(y2 + 64 + tx * 4) = make_float4(acc2[i][4], acc2[i][5], acc2[i][6], acc2[i][7]);
    }
  }
}

// =================== fully fused head (Round-6-bench structure + swizzled xsT) ===================
// Main loop: acc = X@W1 (proj1, cols tx*8..+7), accc = X@Wc1 (cls1, cols tx*4..+3).
// Epilogue: S. Phase C: out_z = relu(z1)@W2 via LDS transpose; acc indices STATIC (j only).
__global__ __launch_bounds__(256, 3) void k_head_fused(
    const float* __restrict__ X, const float* __restrict__ inb,
    const float* __restrict__ W1, const float* __restrict__ b1,
    const float* __restrict__ W2, const float* __restrict__ b2,
    const float* __restrict__ Wc1, const float* __restrict__ bc1,
    const float* __restrict__ Wc2, const float* __restrict__ bc2,
    float* __restrict__ Z, float* __restrict__ S, int N) {
  __shared__ float xsT[32][132];
  __shared__ float ws[32][128];
  __shared__ float ws2[32][64];
  __shared__ float bsl[128];
  __shared__ float inbs[128];
  __shared__ float bsc[64];
  __shared__ float wc2s[64];
  for (int i = threadIdx.x; i < 128; i += 256) { bsl[i] = b1[i]; inbs[i] = inb[i]; }
  if (threadIdx.x < 64) { bsc[threadIdx.x] = bc1[threadIdx.x]; wc2s[threadIdx.x] = Wc2[threadIdx.x]; }
  __syncthreads();
  int row0 = blockIdx.x * 128;
  int tx = threadIdx.x & 15, ty = threadIdx.x >> 4;
  int ty8 = ty * 8;
  float acc[8][8], accc[8][4];
#pragma unroll
  for (int j = 0; j < 8; ++j) {
    float bj = bsl[tx * 8 + j];
#pragma unroll
    for (int i = 0; i < 8; ++i) acc[i][j] = bj;
  }
#pragma unroll
  for (int j = 0; j < 4; ++j) {
    float bj = bsc[tx * 4 + j];
#pragma unroll
    for (int i = 0; i < 8; ++i) accc[i][j] = bj;
  }
  // -------- main loop: single X pass feeds proj1 + cls1 --------
  for (int ch = 0; ch < 4; ++ch) {
    int k0 = ch * 32;
    for (int idx = threadIdx.x; idx < 128 * 8; idx += 256) {
      int f = idx & 7, r = idx >> 3;
      int row = row0 + r;
      float4 v = make_float4(0.f, 0.f, 0.f, 0.f);
      if (row < N) {
        v = *(const float4*)(X + (size_t)row * 128 + k0 + f * 4);
        v.x += inbs[k0 + f * 4 + 0]; v.y += inbs[k0 + f * 4 + 1];
        v.z += inbs[k0 + f * 4 + 2]; v.w += inbs[k0 + f * 4 + 3];
      }
      int rx = r ^ ((f & 3) << 3);
      xsT[f * 4 + 0][rx] = v.x; xsT[f * 4 + 1][rx] = v.y;
      xsT[f * 4 + 2][rx] = v.z; xsT[f * 4 + 3][rx] = v.w;
    }
    for (int idx = threadIdx.x; idx < 32 * 32; idx += 256) {
      int c4 = (idx & 31) * 4, kk = idx >> 5;
      *(float4*)&ws[kk][c4] = *(const float4*)(W1 + (size_t)(k0 + kk) * 128 + c4);
    }
    for (int idx = threadIdx.x; idx < 32 * 16; idx += 256) {
      int c4 = (idx & 15) * 4, kk = idx >> 4;
      *(float4*)&ws2[kk][c4] = *(const float4*)(Wc1 + (size_t)(k0 + kk) * 64 + c4);
    }
    __syncthreads();
#pragma unroll
    for (int k = 0; k < 32; ++k) {
      int g8 = ((k >> 2) & 3) << 3;
      float4 a0 = *(const float4*)&xsT[k][(ty8 ^ g8)];
      float4 a1 = *(const float4*)&xsT[k][(ty8 ^ g8) + 4];
      float4 b0 = *(const float4*)&ws[k][tx * 8];
      float4 b1v = *(const float4*)&ws[k][tx * 8 + 4];
      float4 cv = *(const float4*)&ws2[k][tx * 4];
      float av[8] = {a0.x, a0.y, a0.z, a0.w, a1.x, a1.y, a1.z, a1.w};
      float bv[8] = {b0.x, b0.y, b0.z, b0.w, b1v.x, b1v.y, b1v.z, b1v.w};
#pragma unroll
      for (int i = 0; i < 8; ++i) {
#pragma unroll
        for (int j = 0; j < 8; ++j) acc[i][j] += av[i] * bv[j];
        accc[i][0] += av[i] * cv.x; accc[i][1] += av[i] * cv.y;
        accc[i][2] += av[i] * cv.z; accc[i][3] += av[i] * cv.w;
      }
    }
    __syncthreads();
  }
  // -------- cls epilogue --------
  {
    float w2a = wc2s[tx * 4], w2b = wc2s[tx * 4 + 1], w2c = wc2s[tx * 4 + 2], w2d = wc2s[tx * 4 + 3];
    float bb2 = bc2[0];
#pragma unroll
    for (int i = 0; i < 8; ++i) {
      float p = fmaxf(accc[i][0], 0.f) * w2a + fmaxf(accc[i][1], 0.f) * w2b +
                fmaxf(accc[i][2], 0.f) * w2c + fmaxf(accc[i][3], 0.f) * w2d;
      p += __shfl_xor(p, 1, 16);
      p += __shfl_xor(p, 2, 16);
      p += __shfl_xor(p, 4, 16);
      p += __shfl_xor(p, 8, 16);
      int row = row0 + ty8 + i;
      if (row < N && tx == 0) S[row] = 1.f / (1.f + __expf(-(p + bb2)));
    }
  }
  // -------- phase C: out_z = relu(z1)@W2 + b2 (z1 never hits global) --------
  float acc3[8][8];
#pragma unroll
  for (int j = 0; j < 8; ++j) {
    float bj = b2[tx * 8 + j];
#pragma unroll
    for (int i = 0; i < 8; ++i) acc3[i][j] = bj;
  }
  for (int ch = 0; ch < 4; ++ch) {
    // z1 cols [32ch, 32ch+32) live in threads with tx>>2 == ch; acc index j is STATIC
    if ((tx >> 2) == ch) {
#pragma unroll
      for (int j = 0; j < 8; ++j) {
        int colk = (tx & 3) * 8 + j;
        int rg8 = ((colk >> 2) & 3) << 3;
        int base = ty8 ^ rg8;
        *(float4*)&xsT[colk][base] =
            make_float4(fmaxf(acc[0][j], 0.f), fmaxf(acc[1][j], 0.f),
                        fmaxf(acc[2][j], 0.f), fmaxf(acc[3][j], 0.f));
        *(float4*)&xsT[colk][base + 4] =
            make_float4(fmaxf(acc[4][j], 0.f), fmaxf(acc[5][j], 0.f),
                        fmaxf(acc[6][j], 0.f), fmaxf(acc[7][j], 0.f));
      }
    }
    for (int idx = threadIdx.x; idx < 32 * 32; idx += 256) {
      int c4 = (idx & 31) * 4, kk = idx >> 5;
      *(float4*)&ws[kk][c4] = *(const float4*)(W2 + (size_t)(ch * 32 + kk) * 128 + c4);
    }
    __syncthreads();
#pragma unroll
    for (int k = 0; k < 32; ++k) {
      int g8 = ((k >> 2) & 3) << 3;
      float4 a0 = *(const float4*)&xsT[k][(ty8 ^ g8)];
      float4 a1 = *(const float4*)&xsT[k][(ty8 ^ g8) + 4];
      float4 b0 = *(const float4*)&ws[k][tx * 8];
      float4 b1v = *(const float4*)&ws[k][tx * 8 + 4];
      float av[8] = {a0.x, a0.y, a0.z, a0.w, a1.x, a1.y, a1.z, a1.w};
      float bv[8] = {b0.x, b0.y, b0.z, b0.w, b1v.x, b1v.y, b1v.z, b1v.w};
#pragma unroll
      for (int i = 0; i < 8; ++i)
#pragma unroll
        for (int j = 0; j < 8; ++j) acc3[i][j] += av[i] * bv[j];
    }
    __syncthreads();
  }
#pragma unroll
  for (int i = 0; i < 8; ++i) {
    int row = row0 + ty8 + i;
    if (row < N) {
      float* zr = Z + (size_t)row * 128 + tx * 8;
      *(float4*)zr = make_float4(acc3[i][0], acc3[i][1], acc3[i][2], acc3[i][3]);
      *(float4*)(zr + 4) = make_float4(acc3[i][4], acc3[i][5], acc3[i][6], acc3[i][7]);
    }
  }
}

// =================== CSR build (fused both directions) ===================

__global__ __launch_bounds__(256) void k_hist2(
    const int* __restrict__ src, const int* __restrict__ dst,
    int* __restrict__ histD, int* __restrict__ histS, int E) {
  int e = blockIdx.x * 256 + threadIdx.x;
  if (e >= E) return;
  atomicAdd(&histD[dst[e]], 1);
  atomicAdd(&histS[src[e]], 1);
}

#define SCAN_T 256
#define SCAN_V 4
#define SCAN_BLK 1024

__global__ __launch_bounds__(SCAN_T) void k_scan_local(
    const int* __restrict__ hist, int* __restrict__ starts,
    int* __restrict__ partials, int N) {
  __shared__ int sums[SCAN_T];
  int base = blockIdx.x * SCAN_BLK + threadIdx.x * SCAN_V;
  int v[SCAN_V];
  int s = 0;
#pragma unroll
  for (int i = 0; i < SCAN_V; ++i) { v[i] = (base + i < N) ? hist[base + i] : 0; s += v[i]; }
  sums[threadIdx.x] = s;
  __syncthreads();
  for (int off = 1; off < SCAN_T; off <<= 1) {
    int x = (threadIdx.x >= off) ? sums[threadIdx.x - off] : 0;
    __syncthreads();
    sums[threadIdx.x] += x;
    __syncthreads();
  }
  int run = (threadIdx.x > 0) ? sums[threadIdx.x - 1] : 0;
#pragma unroll
  for (int i = 0; i < SCAN_V; ++i) {
    if (base + i < N) starts[base + i] = run;
    run += v[i];
  }
  if (threadIdx.x == SCAN_T - 1) partials[blockIdx.x] = sums[SCAN_T - 1];
}

__global__ __launch_bounds__(SCAN_T) void k_scan_partials(int* partials, int nb) {
  __shared__ int s[SCAN_T];
  s[threadIdx.x] = (threadIdx.x < nb) ? partials[threadIdx.x] : 0;
  __syncthreads();
  for (int off = 1; off < SCAN_T; off <<= 1) {
    int x = (threadIdx.x >= off) ? s[threadIdx.x - off] : 0;
    __syncthreads();
    s[threadIdx.x] += x;
    __syncthreads();
  }
  if (threadIdx.x < nb) partials[threadIdx.x] = (threadIdx.x > 0) ? s[threadIdx.x - 1] : 0;
}

__global__ __launch_bounds__(256) void k_scan_add(
    int* __restrict__ starts, const int* __restrict__ partials,
    int* __restrict__ cursor, int N) {
  int i = blockIdx.x * 256 + threadIdx.x;
  if (i >= N) return;
  int v = starts[i] + partials[i / SCAN_BLK];
  starts[i] = v;
  cursor[i] = v;
}

__global__ __launch_bounds__(256) void k_scatter2(
    const int* __restrict__ src, const int* __restrict__ dst,
    int* __restrict__ cur1, int* __restrict__ cur2,
    int2* __restrict__ ebuf1, int2* __restrict__ ebuf2, int E) {
  int e = blockIdx.x * 256 + threadIdx.x;
  if (e >= E) return;
  int s = src[e], d = dst[e];
  int p1 = atomicAdd(&cur1[d], 1);
  ebuf1[p1] = make_int2(s, e);
  int p2 = atomicAdd(&cur2[s], 1);
  ebuf2[p2] = make_int2(d, e);
}

// =================== fused GATv2 edge phase (gather-only, online softmax) ===================
template <int USE_EF>
__global__ __launch_bounds__(256) void k_gat(
    const float* __restrict__ xl, const float* __restrict__ xr,
    const int2* __restrict__ ebuf, const int* __restrict__ starts,
    const int* __restrict__ counts, const float* __restrict__ att,
    const float* __restrict__ eattr, const float* __restrict__ We,
    float* __restrict__ agg, int N) {
  int wid = (blockIdx.x * 256 + threadIdx.x) >> 6;
  if (wid >= N) return;
  int lane = threadIdx.x & 63;
  int g = lane >> 4;
  int t = lane & 15;
  int c = g * 32 + t * 2;
  float att0 = att[c], att1 = att[c + 1];
  float2 we0, we1, we2;
  if (USE_EF) {
    we0 = *(const float2*)(We + 0 * HC + c);
    we1 = *(const float2*)(We + 1 * HC + c);
    we2 = *(const float2*)(We + 2 * HC + c);
  }
  float2 xrv = *(const float2*)(xr + (size_t)wid * HC + c);
  int st = starts[wid], cnt = counts[wid];
  float m = -3.402823466e38f, dsum = 0.f, a0 = 0.f, a1 = 0.f;
  for (int i = 0; i < cnt; ++i) {
    int2 se = ebuf[st + i];
    float2 xlv = *(const float2*)(xl + (size_t)se.x * HC + c);
    float x0 = xlv.x + xrv.x, x1 = xlv.y + xrv.y;
    if (USE_EF) {
      const float* ea = eattr + (size_t)se.y * 3;
      float e0 = ea[0], e1 = ea[1], e2 = ea[2];
      x0 += e0 * we0.x + e1 * we1.x + e2 * we2.x;
      x1 += e0 * we0.y + e1 * we1.y + e2 * we2.y;
    }
    x0 = (x0 > 0.f) ? x0 : 0.2f * x0;
    x1 = (x1 > 0.f) ? x1 : 0.2f * x1;
    float p = x0 * att0 + x1 * att1;
    p += __shfl_xor(p, 1, 16);
    p += __shfl_xor(p, 2, 16);
    p += __shfl_xor(p, 4, 16);
    p += __shfl_xor(p, 8, 16);
    float newm = fmaxf(m, p);
    float scale = __expf(m - newm);
    float w = __expf(p - newm);
    dsum = dsum * scale + w;
    a0 = a0 * scale + w * xlv.x;
    a1 = a1 * scale + w * xlv.y;
    m = newm;
  }
  float inv = (dsum > 0.f) ? 1.f / dsum : 0.f;
  *(float2*)(agg + (size_t)wid * HC + c) = make_float2(a0 * inv, a1 * inv);
}

static inline int imin(int a, int b) { return a < b ? a : b; }

extern "C" void kernel_launch(void* const* d_in, const int* in_sizes, int n_in,
                              void* d_out, int out_size, void* d_ws, size_t ws_size,
                              hipStream_t stream) {
  const float* customer_x = (const float*)d_in[0];
  const float* fund_x     = (const float*)d_in[1];
  const int*   edge_src   = (const int*)d_in[2];
  const int*   edge_dst   = (const int*)d_in[3];
  const float* edge_attr  = (const float*)d_in[4];
  const float* user_W = (const float*)d_in[5];
  const float* user_b = (const float*)d_in[6];
  const float* item_W = (const float*)d_in[7];
  const float* item_b = (const float*)d_in[8];
  const float* c1_Wl = (const float*)d_in[9];
  const float* c1_bl = (const float*)d_in[10];
  const float* c1_Wr = (const float*)d_in[11];
  const float* c1_br = (const float*)d_in[12];
  const float* c1_att = (const float*)d_in[13];
  const float* c1_We  = (const float*)d_in[14];
  const float* c1_bias = (const float*)d_in[15];
  const float* c2_Wl = (const float*)d_in[16];
  const float* c2_bl = (const float*)d_in[17];
  const float* c2_Wr = (const float*)d_in[18];
  const float* c2_br = (const float*)d_in[19];
  const float* c2_att = (const float*)d_in[20];
  const float* c2_bias = (const float*)d_in[21];
  const float* proj_W1 = (const float*)d_in[22];
  const float* proj_b1 = (const float*)d_in[23];
  const float* proj_W2 = (const float*)d_in[24];
  const float* proj_b2 = (const float*)d_in[25];
  const float* cls_W1 = (const float*)d_in[26];
  const float* cls_b1 = (const float*)d_in[27];
  const float* cls_W2 = (const float*)d_in[28];
  const float* cls_b2 = (const float*)d_in[29];

  const int Ncust = in_sizes[0] / 101;
  const int Nitem = in_sizes[1];
  const int E     = in_sizes[2];

  // -------- workspace layout (~141 MiB) --------
  float* w = (float*)d_ws;
  float* user_x  = w; w += (size_t)Ncust * 32;
  float* item_x0 = w; w += (size_t)Nitem * 32;
  float* bufC    = w; w += (size_t)Ncust * HC;   // xl1 -> (conv2 xl2 in first Nitem rows)
  float* bufD    = w; w += (size_t)Nitem * HC;   // xr1 -> agg1 (in-place)
  float* bufE    = w; w += (size_t)Ncust * HC;   // xr2 -> agg2 (in-place)
  int* hist1   = (int*)w; w += Nitem;            // hist1+hist2 adjacent: single memset
  int* hist2   = (int*)w; w += Ncust;
  int* starts1 = (int*)w; w += Nitem;
  int* cursor1 = (int*)w; w += Nitem;
  int* starts2 = (int*)w; w += Ncust;
  int* cursor2 = (int*)w; w += Ncust;
  int* partials = (int*)w; w += 512;
  int2* ebuf1 = (int2*)w; w += (size_t)E * 2;
  int2* ebuf2 = (int2*)w; w += (size_t)E * 2;
  if ((size_t)((char*)w - (char*)d_ws) > ws_size) return;

  float* out_scores = (float*)d_out;
  float* out_z      = out_scores + Ncust;

  const int egrid = (E + 255) / 256;
  const int nb1 = (Nitem + SCAN_BLK - 1) / SCAN_BLK;
  const int nb2 = (Ncust + SCAN_BLK - 1) / SCAN_BLK;
  const int nt1 = (Ncust + 127) / 128;
  const int nt2 = (Nitem + 127) / 128;

  // -------- CSR build (fused passes) --------
  hipMemsetAsync(hist1, 0, (size_t)(Nitem + Ncust) * 4, stream);
  k_hist2<<<egrid, 256, 0, stream>>>(edge_src, edge_dst, hist1, hist2, E);
  k_scan_local<<<nb1, SCAN_T, 0, stream>>>(hist1, starts1, partials, Nitem);
  k_scan_partials<<<1, SCAN_T, 0, stream>>>(partials, nb1);
  k_scan_add<<<(Nitem + 255) / 256, 256, 0, stream>>>(starts1, partials, cursor1, Nitem);
  k_scan_local<<<nb2, SCAN_T, 0, stream>>>(hist2, starts2, partials, Ncust);
  k_scan_partials<<<1, SCAN_T, 0, stream>>>(partials, nb2);
  k_scan_add<<<(Ncust + 255) / 256, 256, 0, stream>>>(starts2, partials, cursor2, Ncust);
  k_scatter2<<<egrid, 256, 0, stream>>>(edge_src, edge_dst, cursor1, cursor2, ebuf1, ebuf2, E);

  // -------- node projections --------
  k_proj101<<<(Ncust + 63) / 64, 256, 0, stream>>>(customer_x, user_W, user_b, user_x, Ncust);
  k_item_proj<<<(Nitem * 32 + 255) / 256, 256, 0, stream>>>(fund_x, item_W, item_b, item_x0, Nitem);

  // -------- conv linear parts from user_x (xl1 + xr2 in one pass) --------
  k_dual32<<<nt1, 256, 0, stream>>>(user_x, c1_Wl, c1_bl, c2_Wr, c2_br, bufC, bufE, Ncust);
  k_tile<32, 0, 0><<<nt2, 256, 0, stream>>>(item_x0, nullptr, c1_Wr, c1_br, bufD, Nitem);

  // -------- conv1 edge phase (customer -> fund), agg1 in-place into bufD --------
  k_gat<1><<<(Nitem + 3) / 4, 256, 0, stream>>>(bufC, bufD, ebuf1, starts1, hist1,
                                                c1_att, edge_attr, c1_We, bufD, Nitem);

  // -------- conv2: xl2 then edge phase (fund -> customer) in-place bufE --------
  k_tile<128, 1, 0><<<nt2, 256, 0, stream>>>(bufD, c1_bias, c2_Wl, c2_bl, bufC, Nitem);
  k_gat<0><<<(Ncust + 3) / 4, 256, 0, stream>>>(bufC, bufE, ebuf2, starts2, hist2,
                                                c2_att, nullptr, nullptr, bufE, Ncust);

  // -------- fused head: proj1 + cls + proj2 --------
  k_head_fused<<<nt1, 256, 0, stream>>>(bufE, c2_bias, proj_W1, proj_b1, proj_W2, proj_b2,
                                        cls_W1, cls_b1, cls_W2, cls_b2,
                                        out_z, out_scores, Ncust);
}

// Round 10
// 532.027 us; speedup vs baseline: 6.8144x; 3.3607x over previous
//
#include <hip/hip_runtime.h>
#include <math.h>

#define HH 4
#define CC 32
#define HC 128

__device__ __forceinline__ float relu4x(float v) { return fmaxf(v, 0.f); }

// =================== node projection: customer_x[101] -> user_x[32] ===================
__global__ __launch_bounds__(256) void k_proj101(
    const float* __restrict__ X, const float* __restrict__ W,
    const float* __restrict__ b, float* __restrict__ Y, int N) {
  __shared__ float xs[64][105];
  __shared__ float Ws[101 * 32];
  __shared__ float bs[32];
  for (int i = threadIdx.x; i < 101 * 32; i += 256) Ws[i] = W[i];
  if (threadIdx.x < 32) bs[threadIdx.x] = b[threadIdx.x];
  int row0 = blockIdx.x * 64;
  for (int idx = threadIdx.x; idx < 64 * 25; idx += 256) {
    int f = idx % 25, r = idx / 25;
    int row = row0 + r;
    float4 v = make_float4(0.f, 0.f, 0.f, 0.f);
    if (row < N) v = *(const float4*)(X + (size_t)row * 101 + f * 4);
    xs[r][f * 4 + 0] = v.x; xs[r][f * 4 + 1] = v.y;
    xs[r][f * 4 + 2] = v.z; xs[r][f * 4 + 3] = v.w;
  }
  if (threadIdx.x < 64) {
    int row = row0 + threadIdx.x;
    xs[threadIdx.x][100] = (row < N) ? X[(size_t)row * 101 + 100] : 0.f;
  }
  __syncthreads();
  int q = threadIdx.x & 3;
  int r = threadIdx.x >> 2;
  float acc[8];
#pragma unroll
  for (int j = 0; j < 8; ++j) acc[j] = bs[q * 8 + j];
  for (int k = 0; k < 101; ++k) {
    float xv = xs[r][k];
    float4 w0 = *(const float4*)&Ws[k * 32 + q * 8];
    float4 w1 = *(const float4*)&Ws[k * 32 + q * 8 + 4];
    acc[0] += xv * w0.x; acc[1] += xv * w0.y; acc[2] += xv * w0.z; acc[3] += xv * w0.w;
    acc[4] += xv * w1.x; acc[5] += xv * w1.y; acc[6] += xv * w1.z; acc[7] += xv * w1.w;
  }
  int row = row0 + r;
  if (row < N) {
    float* yr = Y + (size_t)row * 32 + q * 8;
    *(float4*)yr = make_float4(acc[0], acc[1], acc[2], acc[3]);
    *(float4*)(yr + 4) = make_float4(acc[4], acc[5], acc[6], acc[7]);
  }
}

__global__ __launch_bounds__(256) void k_item_proj(
    const float* __restrict__ X, const float* __restrict__ W,
    const float* __restrict__ b, float* __restrict__ Y, int N) {
  int t = blockIdx.x * 256 + threadIdx.x;
  if (t >= N * 32) return;
  int i = t >> 5, c = t & 31;
  Y[t] = X[i] * W[c] + b[c];
}

// =================== K-chunked tiled GEMM (8x8 micro-tile, float4 staging) ===================
template <int K, int INRELU, int OUTRELU>
__global__ __launch_bounds__(256, 3) void k_tile(
    const float* __restrict__ X, const float* __restrict__ inb,
    const float* __restrict__ W, const float* __restrict__ b,
    float* __restrict__ Y, int N) {
  constexpr int KB = 32;
  constexpr int NCH = K / KB;
  __shared__ float xsT[KB][132];
  __shared__ float ws[KB][128];
  __shared__ float bsl[128];
  __shared__ float inbs[K];
  for (int i = threadIdx.x; i < 128; i += 256) bsl[i] = b[i];
  for (int i = threadIdx.x; i < K; i += 256) inbs[i] = inb ? inb[i] : 0.f;
  __syncthreads();
  int row0 = blockIdx.x * 128;
  int tx = threadIdx.x & 15, ty = threadIdx.x >> 4;
  float acc[8][8];
#pragma unroll
  for (int j = 0; j < 8; ++j) {
    float bj = bsl[tx * 8 + j];
#pragma unroll
    for (int i = 0; i < 8; ++i) acc[i][j] = bj;
  }
  for (int ch = 0; ch < NCH; ++ch) {
    int k0 = ch * KB;
    for (int idx = threadIdx.x; idx < 128 * 8; idx += 256) {
      int f = idx & 7, r = idx >> 3;
      int row = row0 + r;
      float4 v = make_float4(0.f, 0.f, 0.f, 0.f);
      if (row < N) {
        v = *(const float4*)(X + (size_t)row * K + k0 + f * 4);
        v.x += inbs[k0 + f * 4 + 0]; v.y += inbs[k0 + f * 4 + 1];
        v.z += inbs[k0 + f * 4 + 2]; v.w += inbs[k0 + f * 4 + 3];
        if (INRELU) { v.x = relu4x(v.x); v.y = relu4x(v.y); v.z = relu4x(v.z); v.w = relu4x(v.w); }
      }
      xsT[f * 4 + 0][r] = v.x; xsT[f * 4 + 1][r] = v.y;
      xsT[f * 4 + 2][r] = v.z; xsT[f * 4 + 3][r] = v.w;
    }
    for (int idx = threadIdx.x; idx < KB * 32; idx += 256) {
      int c4 = (idx & 31) * 4, kk = idx >> 5;
      *(float4*)&ws[kk][c4] = *(const float4*)(W + (size_t)(k0 + kk) * 128 + c4);
    }
    __syncthreads();
#pragma unroll 2
    for (int k = 0; k < KB; ++k) {
      float4 a0 = *(const float4*)&xsT[k][ty * 8];
      float4 a1 = *(const float4*)&xsT[k][ty * 8 + 4];
      float4 b0 = *(const float4*)&ws[k][tx * 8];
      float4 b1 = *(const float4*)&ws[k][tx * 8 + 4];
      float av[8] = {a0.x, a0.y, a0.z, a0.w, a1.x, a1.y, a1.z, a1.w};
      float bv[8] = {b0.x, b0.y, b0.z, b0.w, b1.x, b1.y, b1.z, b1.w};
#pragma unroll
      for (int i = 0; i < 8; ++i)
#pragma unroll
        for (int j = 0; j < 8; ++j) acc[i][j] += av[i] * bv[j];
    }
    __syncthreads();
  }
#pragma unroll
  for (int i = 0; i < 8; ++i) {
    int row = row0 + ty * 8 + i;
    if (row < N) {
      float o[8];
#pragma unroll
      for (int j = 0; j < 8; ++j) o[j] = OUTRELU ? fmaxf(acc[i][j], 0.f) : acc[i][j];
      float* yr = Y + (size_t)row * 128 + tx * 8;
      *(float4*)yr = make_float4(o[0], o[1], o[2], o[3]);
      *(float4*)(yr + 4) = make_float4(o[4], o[5], o[6], o[7]);
    }
  }
}

// =================== dual K=32 GEMM ===================
__global__ __launch_bounds__(256, 3) void k_dual32(
    const float* __restrict__ X,
    const float* __restrict__ W1, const float* __restrict__ b1,
    const float* __restrict__ W2, const float* __restrict__ b2,
    float* __restrict__ Y1, float* __restrict__ Y2, int N) {
  __shared__ float xsT[32][132];
  __shared__ float ws1[32][128];
  __shared__ float ws2[32][128];
  __shared__ float bsa[128];
  __shared__ float bsb[128];
  for (int i = threadIdx.x; i < 128; i += 256) { bsa[i] = b1[i]; bsb[i] = b2[i]; }
  int row0 = blockIdx.x * 128;
  for (int idx = threadIdx.x; idx < 128 * 8; idx += 256) {
    int f = idx & 7, r = idx >> 3;
    int row = row0 + r;
    float4 v = make_float4(0.f, 0.f, 0.f, 0.f);
    if (row < N) v = *(const float4*)(X + (size_t)row * 32 + f * 4);
    xsT[f * 4 + 0][r] = v.x; xsT[f * 4 + 1][r] = v.y;
    xsT[f * 4 + 2][r] = v.z; xsT[f * 4 + 3][r] = v.w;
  }
  for (int idx = threadIdx.x; idx < 32 * 32; idx += 256) {
    int c4 = (idx & 31) * 4, kk = idx >> 5;
    *(float4*)&ws1[kk][c4] = *(const float4*)(W1 + (size_t)kk * 128 + c4);
    *(float4*)&ws2[kk][c4] = *(const float4*)(W2 + (size_t)kk * 128 + c4);
  }
  __syncthreads();
  int tx = threadIdx.x & 15, ty = threadIdx.x >> 4;
  float acc1[8][8], acc2[8][8];
#pragma unroll
  for (int j = 0; j < 8; ++j) {
    float c1 = bsa[tx * 8 + j], c2 = bsb[tx * 8 + j];
#pragma unroll
    for (int i = 0; i < 8; ++i) { acc1[i][j] = c1; acc2[i][j] = c2; }
  }
#pragma unroll 2
  for (int k = 0; k < 32; ++k) {
    float4 a0 = *(const float4*)&xsT[k][ty * 8];
    float4 a1 = *(const float4*)&xsT[k][ty * 8 + 4];
    float4 p0 = *(const float4*)&ws1[k][tx * 8];
    float4 p1 = *(const float4*)&ws1[k][tx * 8 + 4];
    float4 q0 = *(const float4*)&ws2[k][tx * 8];
    float4 q1 = *(const float4*)&ws2[k][tx * 8 + 4];
    float av[8] = {a0.x, a0.y, a0.z, a0.w, a1.x, a1.y, a1.z, a1.w};
    float pv[8] = {p0.x, p0.y, p0.z, p0.w, p1.x, p1.y, p1.z, p1.w};
    float qv[8] = {q0.x, q0.y, q0.z, q0.w, q1.x, q1.y, q1.z, q1.w};
#pragma unroll
    for (int i = 0; i < 8; ++i)
#pragma unroll
      for (int j = 0; j < 8; ++j) { acc1[i][j] += av[i] * pv[j]; acc2[i][j] += av[i] * qv[j]; }
  }
#pragma unroll
  for (int i = 0; i < 8; ++i) {
    int row = row0 + ty * 8 + i;
    if (row < N) {
      float* y1 = Y1 + (size_t)row * 128 + tx * 8;
      float* y2 = Y2 + (size_t)row * 128 + tx * 8;
      *(float4*)y1 = make_float4(acc1[i][0], acc1[i][1], acc1[i][2], acc1[i][3]);
      *(float4*)(y1 + 4) = make_float4(acc1[i][4], acc1[i][5], acc1[i][6], acc1[i][7]);
      *(float4*)y2 = make_float4(acc2[i][0], acc2[i][1], acc2[i][2], acc2[i][3]);
      *(float4*)(y2 + 4) = make_float4(acc2[i][4], acc2[i][5], acc2[i][6], acc2[i][7]);
    }
  }
}

// =================== fully fused head (R6-proven structure) ===================
__global__ __launch_bounds__(256, 3) void k_head_fused(
    const float* __restrict__ X, const float* __restrict__ inb,
    const float* __restrict__ W1, const float* __restrict__ b1,
    const float* __restrict__ W2, const float* __restrict__ b2,
    const float* __restrict__ Wc1, const float* __restrict__ bc1,
    const float* __restrict__ Wc2, const float* __restrict__ bc2,
    float* __restrict__ Z, float* __restrict__ S, int N) {
  __shared__ float xsT[32][132];
  __shared__ float ws[32][128];
  __shared__ float ws2[32][64];
  __shared__ float bsl[128];
  __shared__ float inbs[128];
  __shared__ float bsc[64];
  __shared__ float wc2s[64];
  for (int i = threadIdx.x; i < 128; i += 256) { bsl[i] = b1[i]; inbs[i] = inb[i]; }
  if (threadIdx.x < 64) { bsc[threadIdx.x] = bc1[threadIdx.x]; wc2s[threadIdx.x] = Wc2[threadIdx.x]; }
  __syncthreads();
  int row0 = blockIdx.x * 128;
  int tx = threadIdx.x & 15, ty = threadIdx.x >> 4;
  float acc[8][8], accc[8][4];
#pragma unroll
  for (int j = 0; j < 8; ++j) {
    float bj = bsl[tx * 8 + j];
#pragma unroll
    for (int i = 0; i < 8; ++i) acc[i][j] = bj;
  }
#pragma unroll
  for (int j = 0; j < 4; ++j) {
    float bj = bsc[tx * 4 + j];
#pragma unroll
    for (int i = 0; i < 8; ++i) accc[i][j] = bj;
  }
  // -------- main loop: single X pass feeds proj1 + cls1 --------
  for (int ch = 0; ch < 4; ++ch) {
    int k0 = ch * 32;
    for (int idx = threadIdx.x; idx < 128 * 8; idx += 256) {
      int f = idx & 7, r = idx >> 3;
      int row = row0 + r;
      float4 v = make_float4(0.f, 0.f, 0.f, 0.f);
      if (row < N) {
        v = *(const float4*)(X + (size_t)row * 128 + k0 + f * 4);
        v.x += inbs[k0 + f * 4 + 0]; v.y += inbs[k0 + f * 4 + 1];
        v.z += inbs[k0 + f * 4 + 2]; v.w += inbs[k0 + f * 4 + 3];
      }
      xsT[f * 4 + 0][r] = v.x; xsT[f * 4 + 1][r] = v.y;
      xsT[f * 4 + 2][r] = v.z; xsT[f * 4 + 3][r] = v.w;
    }
    for (int idx = threadIdx.x; idx < 32 * 32; idx += 256) {
      int c4 = (idx & 31) * 4, kk = idx >> 5;
      *(float4*)&ws[kk][c4] = *(const float4*)(W1 + (size_t)(k0 + kk) * 128 + c4);
    }
    for (int idx = threadIdx.x; idx < 32 * 16; idx += 256) {
      int c4 = (idx & 15) * 4, kk = idx >> 4;
      *(float4*)&ws2[kk][c4] = *(const float4*)(Wc1 + (size_t)(k0 + kk) * 64 + c4);
    }
    __syncthreads();
#pragma unroll 2
    for (int k = 0; k < 32; ++k) {
      float4 a0 = *(const float4*)&xsT[k][ty * 8];
      float4 a1 = *(const float4*)&xsT[k][ty * 8 + 4];
      float4 b0 = *(const float4*)&ws[k][tx * 8];
      float4 b1v = *(const float4*)&ws[k][tx * 8 + 4];
      float4 cv = *(const float4*)&ws2[k][tx * 4];
      float av[8] = {a0.x, a0.y, a0.z, a0.w, a1.x, a1.y, a1.z, a1.w};
      float bv[8] = {b0.x, b0.y, b0.z, b0.w, b1v.x, b1v.y, b1v.z, b1v.w};
#pragma unroll
      for (int i = 0; i < 8; ++i) {
#pragma unroll
        for (int j = 0; j < 8; ++j) acc[i][j] += av[i] * bv[j];
        accc[i][0] += av[i] * cv.x; accc[i][1] += av[i] * cv.y;
        accc[i][2] += av[i] * cv.z; accc[i][3] += av[i] * cv.w;
      }
    }
    __syncthreads();
  }
  // -------- cls epilogue --------
  {
    float w2a = wc2s[tx * 4], w2b = wc2s[tx * 4 + 1], w2c = wc2s[tx * 4 + 2], w2d = wc2s[tx * 4 + 3];
    float bb2 = bc2[0];
#pragma unroll
    for (int i = 0; i < 8; ++i) {
      float p = fmaxf(accc[i][0], 0.f) * w2a + fmaxf(accc[i][1], 0.f) * w2b +
                fmaxf(accc[i][2], 0.f) * w2c + fmaxf(accc[i][3], 0.f) * w2d;
      p += __shfl_xor(p, 1, 16);
      p += __shfl_xor(p, 2, 16);
      p += __shfl_xor(p, 4, 16);
      p += __shfl_xor(p, 8, 16);
      int row = row0 + ty * 8 + i;
      if (row < N && tx == 0) S[row] = 1.f / (1.f + __expf(-(p + bb2)));
    }
  }
  // -------- phase C: out_z = relu(z1)@W2 + b2 (z1 never hits global) --------
  float acc3[8][8];
#pragma unroll
  for (int j = 0; j < 8; ++j) {
    float bj = b2[tx * 8 + j];
#pragma unroll
    for (int i = 0; i < 8; ++i) acc3[i][j] = bj;
  }
  for (int ch = 0; ch < 4; ++ch) {
    // z1 cols [32ch, 32ch+32) live in threads with tx>>2 == ch; acc index j is STATIC
    if ((tx >> 2) == ch) {
#pragma unroll
      for (int j = 0; j < 8; ++j) {
        int colk = (tx & 3) * 8 + j;
        *(float4*)&xsT[colk][ty * 8] =
            make_float4(fmaxf(acc[0][j], 0.f), fmaxf(acc[1][j], 0.f),
                        fmaxf(acc[2][j], 0.f), fmaxf(acc[3][j], 0.f));
        *(float4*)&xsT[colk][ty * 8 + 4] =
            make_float4(fmaxf(acc[4][j], 0.f), fmaxf(acc[5][j], 0.f),
                        fmaxf(acc[6][j], 0.f), fmaxf(acc[7][j], 0.f));
      }
    }
    for (int idx = threadIdx.x; idx < 32 * 32; idx += 256) {
      int c4 = (idx & 31) * 4, kk = idx >> 5;
      *(float4*)&ws[kk][c4] = *(const float4*)(W2 + (size_t)(ch * 32 + kk) * 128 + c4);
    }
    __syncthreads();
#pragma unroll 2
    for (int k = 0; k < 32; ++k) {
      float4 a0 = *(const float4*)&xsT[k][ty * 8];
      float4 a1 = *(const float4*)&xsT[k][ty * 8 + 4];
      float4 b0 = *(const float4*)&ws[k][tx * 8];
      float4 b1v = *(const float4*)&ws[k][tx * 8 + 4];
      float av[8] = {a0.x, a0.y, a0.z, a0.w, a1.x, a1.y, a1.z, a1.w};
      float bv[8] = {b0.x, b0.y, b0.z, b0.w, b1v.x, b1v.y, b1v.z, b1v.w};
#pragma unroll
      for (int i = 0; i < 8; ++i)
#pragma unroll
        for (int j = 0; j < 8; ++j) acc3[i][j] += av[i] * bv[j];
    }
    __syncthreads();
  }
#pragma unroll
  for (int i = 0; i < 8; ++i) {
    int row = row0 + ty * 8 + i;
    if (row < N) {
      float* zr = Z + (size_t)row * 128 + tx * 8;
      *(float4*)zr = make_float4(acc3[i][0], acc3[i][1], acc3[i][2], acc3[i][3]);
      *(float4*)(zr + 4) = make_float4(acc3[i][4], acc3[i][5], acc3[i][6], acc3[i][7]);
    }
  }
}

// =================== CSR build (fused both directions) ===================

__global__ __launch_bounds__(256) void k_hist2(
    const int* __restrict__ src, const int* __restrict__ dst,
    int* __restrict__ histD, int* __restrict__ histS, int E) {
  int e = blockIdx.x * 256 + threadIdx.x;
  if (e >= E) return;
  atomicAdd(&histD[dst[e]], 1);
  atomicAdd(&histS[src[e]], 1);
}

#define SCAN_T 256
#define SCAN_V 4
#define SCAN_BLK 1024

__global__ __launch_bounds__(SCAN_T) void k_scan_local(
    const int* __restrict__ hist, int* __restrict__ starts,
    int* __restrict__ partials, int N) {
  __shared__ int sums[SCAN_T];
  int base = blockIdx.x * SCAN_BLK + threadIdx.x * SCAN_V;
  int v[SCAN_V];
  int s = 0;
#pragma unroll
  for (int i = 0; i < SCAN_V; ++i) { v[i] = (base + i < N) ? hist[base + i] : 0; s += v[i]; }
  sums[threadIdx.x] = s;
  __syncthreads();
  for (int off = 1; off < SCAN_T; off <<= 1) {
    int x = (threadIdx.x >= off) ? sums[threadIdx.x - off] : 0;
    __syncthreads();
    sums[threadIdx.x] += x;
    __syncthreads();
  }
  int run = (threadIdx.x > 0) ? sums[threadIdx.x - 1] : 0;
#pragma unroll
  for (int i = 0; i < SCAN_V; ++i) {
    if (base + i < N) starts[base + i] = run;
    run += v[i];
  }
  if (threadIdx.x == SCAN_T - 1) partials[blockIdx.x] = sums[SCAN_T - 1];
}

__global__ __launch_bounds__(SCAN_T) void k_scan_partials(int* partials, int nb) {
  __shared__ int s[SCAN_T];
  s[threadIdx.x] = (threadIdx.x < nb) ? partials[threadIdx.x] : 0;
  __syncthreads();
  for (int off = 1; off < SCAN_T; off <<= 1) {
    int x = (threadIdx.x >= off) ? s[threadIdx.x - off] : 0;
    __syncthreads();
    s[threadIdx.x] += x;
    __syncthreads();
  }
  if (threadIdx.x < nb) partials[threadIdx.x] = (threadIdx.x > 0) ? s[threadIdx.x - 1] : 0;
}

__global__ __launch_bounds__(256) void k_scan_add(
    int* __restrict__ starts, const int* __restrict__ partials,
    int* __restrict__ cursor, int N) {
  int i = blockIdx.x * 256 + threadIdx.x;
  if (i >= N) return;
  int v = starts[i] + partials[i / SCAN_BLK];
  starts[i] = v;
  cursor[i] = v;
}

__global__ __launch_bounds__(256) void k_scatter2(
    const int* __restrict__ src, const int* __restrict__ dst,
    int* __restrict__ cur1, int* __restrict__ cur2,
    int2* __restrict__ ebuf1, int2* __restrict__ ebuf2, int E) {
  int e = blockIdx.x * 256 + threadIdx.x;
  if (e >= E) return;
  int s = src[e], d = dst[e];
  int p1 = atomicAdd(&cur1[d], 1);
  ebuf1[p1] = make_int2(s, e);
  int p2 = atomicAdd(&cur2[s], 1);
  ebuf2[p2] = make_int2(d, e);
}

// =================== fused GATv2 edge phase (gather-only, online softmax) ===================
template <int USE_EF>
__global__ __launch_bounds__(256) void k_gat(
    const float* __restrict__ xl, const float* __restrict__ xr,
    const int2* __restrict__ ebuf, const int* __restrict__ starts,
    const int* __restrict__ counts, const float* __restrict__ att,
    const float* __restrict__ eattr, const float* __restrict__ We,
    float* __restrict__ agg, int N) {
  int wid = (blockIdx.x * 256 + threadIdx.x) >> 6;
  if (wid >= N) return;
  int lane = threadIdx.x & 63;
  int g = lane >> 4;
  int t = lane & 15;
  int c = g * 32 + t * 2;
  float att0 = att[c], att1 = att[c + 1];
  float2 we0, we1, we2;
  if (USE_EF) {
    we0 = *(const float2*)(We + 0 * HC + c);
    we1 = *(const float2*)(We + 1 * HC + c);
    we2 = *(const float2*)(We + 2 * HC + c);
  }
  float2 xrv = *(const float2*)(xr + (size_t)wid * HC + c);
  int st = starts[wid], cnt = counts[wid];
  float m = -3.402823466e38f, dsum = 0.f, a0 = 0.f, a1 = 0.f;
  for (int i = 0; i < cnt; ++i) {
    int2 se = ebuf[st + i];
    float2 xlv = *(const float2*)(xl + (size_t)se.x * HC + c);
    float x0 = xlv.x + xrv.x, x1 = xlv.y + xrv.y;
    if (USE_EF) {
      const float* ea = eattr + (size_t)se.y * 3;
      float e0 = ea[0], e1 = ea[1], e2 = ea[2];
      x0 += e0 * we0.x + e1 * we1.x + e2 * we2.x;
      x1 += e0 * we0.y + e1 * we1.y + e2 * we2.y;
    }
    x0 = (x0 > 0.f) ? x0 : 0.2f * x0;
    x1 = (x1 > 0.f) ? x1 : 0.2f * x1;
    float p = x0 * att0 + x1 * att1;
    p += __shfl_xor(p, 1, 16);
    p += __shfl_xor(p, 2, 16);
    p += __shfl_xor(p, 4, 16);
    p += __shfl_xor(p, 8, 16);
    float newm = fmaxf(m, p);
    float scale = __expf(m - newm);
    float w = __expf(p - newm);
    dsum = dsum * scale + w;
    a0 = a0 * scale + w * xlv.x;
    a1 = a1 * scale + w * xlv.y;
    m = newm;
  }
  float inv = (dsum > 0.f) ? 1.f / dsum : 0.f;
  *(float2*)(agg + (size_t)wid * HC + c) = make_float2(a0 * inv, a1 * inv);
}

static inline int imin(int a, int b) { return a < b ? a : b; }

extern "C" void kernel_launch(void* const* d_in, const int* in_sizes, int n_in,
                              void* d_out, int out_size, void* d_ws, size_t ws_size,
                              hipStream_t stream) {
  const float* customer_x = (const float*)d_in[0];
  const float* fund_x     = (const float*)d_in[1];
  const int*   edge_src   = (const int*)d_in[2];
  const int*   edge_dst   = (const int*)d_in[3];
  const float* edge_attr  = (const float*)d_in[4];
  const float* user_W = (const float*)d_in[5];
  const float* user_b = (const float*)d_in[6];
  const float* item_W = (const float*)d_in[7];
  const float* item_b = (const float*)d_in[8];
  const float* c1_Wl = (const float*)d_in[9];
  const float* c1_bl = (const float*)d_in[10];
  const float* c1_Wr = (const float*)d_in[11];
  const float* c1_br = (const float*)d_in[12];
  const float* c1_att = (const float*)d_in[13];
  const float* c1_We  = (const float*)d_in[14];
  const float* c1_bias = (const float*)d_in[15];
  const float* c2_Wl = (const float*)d_in[16];
  const float* c2_bl = (const float*)d_in[17];
  const float* c2_Wr = (const float*)d_in[18];
  const float* c2_br = (const float*)d_in[19];
  const float* c2_att = (const float*)d_in[20];
  const float* c2_bias = (const float*)d_in[21];
  const float* proj_W1 = (const float*)d_in[22];
  const float* proj_b1 = (const float*)d_in[23];
  const float* proj_W2 = (const float*)d_in[24];
  const float* proj_b2 = (const float*)d_in[25];
  const float* cls_W1 = (const float*)d_in[26];
  const float* cls_b1 = (const float*)d_in[27];
  const float* cls_W2 = (const float*)d_in[28];
  const float* cls_b2 = (const float*)d_in[29];

  const int Ncust = in_sizes[0] / 101;
  const int Nitem = in_sizes[1];
  const int E     = in_sizes[2];

  // -------- workspace layout (~141 MiB) --------
  float* w = (float*)d_ws;
  float* user_x  = w; w += (size_t)Ncust * 32;
  float* item_x0 = w; w += (size_t)Nitem * 32;
  float* bufC    = w; w += (size_t)Ncust * HC;   // xl1 -> (conv2 xl2 in first Nitem rows)
  float* bufD    = w; w += (size_t)Nitem * HC;   // xr1 -> agg1 (in-place)
  float* bufE    = w; w += (size_t)Ncust * HC;   // xr2 -> agg2 (in-place)
  int* hist1   = (int*)w; w += Nitem;            // hist1+hist2 adjacent: single memset
  int* hist2   = (int*)w; w += Ncust;
  int* starts1 = (int*)w; w += Nitem;
  int* cursor1 = (int*)w; w += Nitem;
  int* starts2 = (int*)w; w += Ncust;
  int* cursor2 = (int*)w; w += Ncust;
  int* partials = (int*)w; w += 512;
  int2* ebuf1 = (int2*)w; w += (size_t)E * 2;
  int2* ebuf2 = (int2*)w; w += (size_t)E * 2;
  if ((size_t)((char*)w - (char*)d_ws) > ws_size) return;

  float* out_scores = (float*)d_out;
  float* out_z      = out_scores + Ncust;

  const int egrid = (E + 255) / 256;
  const int nb1 = (Nitem + SCAN_BLK - 1) / SCAN_BLK;
  const int nb2 = (Ncust + SCAN_BLK - 1) / SCAN_BLK;
  const int nt1 = (Ncust + 127) / 128;
  const int nt2 = (Nitem + 127) / 128;

  // -------- CSR build (fused passes) --------
  hipMemsetAsync(hist1, 0, (size_t)(Nitem + Ncust) * 4, stream);
  k_hist2<<<egrid, 256, 0, stream>>>(edge_src, edge_dst, hist1, hist2, E);
  k_scan_local<<<nb1, SCAN_T, 0, stream>>>(hist1, starts1, partials, Nitem);
  k_scan_partials<<<1, SCAN_T, 0, stream>>>(partials, nb1);
  k_scan_add<<<(Nitem + 255) / 256, 256, 0, stream>>>(starts1, partials, cursor1, Nitem);
  k_scan_local<<<nb2, SCAN_T, 0, stream>>>(hist2, starts2, partials, Ncust);
  k_scan_partials<<<1, SCAN_T, 0, stream>>>(partials, nb2);
  k_scan_add<<<(Ncust + 255) / 256, 256, 0, stream>>>(starts2, partials, cursor2, Ncust);
  k_scatter2<<<egrid, 256, 0, stream>>>(edge_src, edge_dst, cursor1, cursor2, ebuf1, ebuf2, E);

  // -------- node projections --------
  k_proj101<<<(Ncust + 63) / 64, 256, 0, stream>>>(customer_x, user_W, user_b, user_x, Ncust);
  k_item_proj<<<(Nitem * 32 + 255) / 256, 256, 0, stream>>>(fund_x, item_W, item_b, item_x0, Nitem);

  // -------- conv linear parts from user_x (xl1 + xr2 in one pass) --------
  k_dual32<<<nt1, 256, 0, stream>>>(user_x, c1_Wl, c1_bl, c2_Wr, c2_br, bufC, bufE, Ncust);
  k_tile<32, 0, 0><<<nt2, 256, 0, stream>>>(item_x0, nullptr, c1_Wr, c1_br, bufD, Nitem);

  // -------- conv1 edge phase (customer -> fund), agg1 in-place into bufD --------
  k_gat<1><<<(Nitem + 3) / 4, 256, 0, stream>>>(bufC, bufD, ebuf1, starts1, hist1,
                                                c1_att, edge_attr, c1_We, bufD, Nitem);

  // -------- conv2: xl2 then edge phase (fund -> customer) in-place bufE --------
  k_tile<128, 1, 0><<<nt2, 256, 0, stream>>>(bufD, c1_bias, c2_Wl, c2_bl, bufC, Nitem);
  k_gat<0><<<(Ncust + 3) / 4, 256, 0, stream>>>(bufC, bufE, ebuf2, starts2, hist2,
                                                c2_att, nullptr, nullptr, bufE, Ncust);

  // -------- fused head: proj1 + cls + proj2 --------
  k_head_fused<<<nt1, 256, 0, stream>>>(bufE, c2_bias, proj_W1, proj_b1, proj_W2, proj_b2,
                                        cls_W1, cls_b1, cls_W2, cls_b2,
                                        out_z, out_scores, Ncust);
}